// Round 7
// baseline (170.209 us; speedup 1.0000x reference)
//
#include <hip/hip_runtime.h>
#include <math.h>

// SIREN forward: coords [N,3] -> first(3->5,sin) -> 256 x hidden(5->5,sin) -> final(5->1)
// Output layout: d_out[0..N) = net output, d_out[N..4N) = coords passthrough.
//
// Round 7:
//  - LDS-staged weights. R2-R6 established: issue count is near-minimal
//    (~2.2 busy cyc/pt-layer vs 2.19 floor) and ~20-25% idle is INVARIANT to
//    waves/SIMD and ILP -> stall hits all waves at once. Theory: 32KB weight
//    stream thrashes the ~16KB scalar K$ (16 waves/CU at unsynced layer
//    phases), s_load goes to L2 (~200cyc) with ~1-layer SGPR prefetch depth.
//    Fix: stage all 256*32 prescaled floats (32KB) in LDS once per block;
//    uniform-address ds_read_b128 broadcasts conflict-free at ~120cyc fixed.
//  - Keep: deg-9 poly sin (8 full-rate VALU ops, err ~3e-5/sin), P=2,
//    unroll 4, uniform clamp control flow, weights prescaled by 30/(2pi).

#define SIREN_HID 5
#define SIREN_NLAYERS 256
// 30 / (2*pi)
#define SIREN_REV 4.774648292756860f

// sin(2*pi*z) via degree-9 odd Chebyshev-truncated poly after exact range
// reduction. 8 full-rate VALU ops (rndne, sub, mul, 4x fma, mul).
__device__ __forceinline__ float sinrev(float z) {
    float k  = __builtin_rintf(z);         // v_rndne_f32
    float r  = z - k;                      // exact, r in [-0.5, 0.5]
    float r2 = r * r;
    float p  = fmaf(32.768f,       r2, -74.4734720f);
    p        = fmaf(p,             r2,  81.3648896f);
    p        = fmaf(p,             r2, -41.3310592f);
    p        = fmaf(p,             r2,   6.2830548f);
    return p * r;
}

// ---------------- prep: scale weights into revolution units ----------------
// d_ws layout (floats):
//   [0 .. 8192)        hidden layers: layer l at l*32: w[0..24], b[25..29], pad
//   [8192 .. 8207)     first layer W (5x3, row-major), scaled
//   [8207 .. 8212)     first layer b, scaled
__global__ __launch_bounds__(256)
void siren_prep(const float* __restrict__ Wf, const float* __restrict__ bf,
                const float* __restrict__ Wh, const float* __restrict__ bh,
                float* __restrict__ ws)
{
    int t = blockIdx.x * blockDim.x + threadIdx.x;
    const int total = SIREN_NLAYERS * 32;
    for (int idx = t; idx < total; idx += gridDim.x * blockDim.x) {
        int l = idx >> 5;
        int k = idx & 31;
        float v = 0.0f;
        if (k < 25)      v = Wh[l * 25 + k] * SIREN_REV;
        else if (k < 30) v = bh[l * 5 + (k - 25)] * SIREN_REV;
        ws[idx] = v;
    }
    if (t < 15) ws[total + t]      = Wf[t] * SIREN_REV;
    if (t < 5)  ws[total + 15 + t] = bf[t] * SIREN_REV;
}

// ---------------- main: 2 points/thread, poly sin, LDS weights ----------------
__global__ __launch_bounds__(256)
void siren_fwd7(const float* __restrict__ coords,
                const float* __restrict__ lw,    // [256][32] scaled hidden w/b
                const float* __restrict__ fw,    // [20] scaled first w(15)+b(5)
                const float* __restrict__ Wfin,  // [1][5] (unscaled)
                const float* __restrict__ bfin,  // [1]
                float* __restrict__ out, int N)
{
    __shared__ float slw[SIREN_NLAYERS * 32];   // 32 KB

    // cooperative stage: 2048 float4s over 256 threads (coalesced)
    {
        const float4* g4 = (const float4*)lw;
        float4* s4 = (float4*)slw;
#pragma unroll
        for (int k = 0; k < 8; ++k)
            s4[threadIdx.x + k * 256] = g4[threadIdx.x + k * 256];
    }
    __syncthreads();

    int i = blockIdx.x * blockDim.x + threadIdx.x;
    const int M = N >> 1;                 // pairs
    i = (i < M) ? i : (M - 1);            // uniform clamp, no divergent return

    // two adjacent points: 24B contiguous (float4 + float2)
    const float* cp = coords + 6 * i;
    float4 q0c = *(const float4*)(cp);      // a0 a1 a2 b0
    float2 q1c = *(const float2*)(cp + 4);  // b1 b2
    float a0 = q0c.x, a1 = q0c.y, a2 = q0c.z;
    float b0 = q0c.w, b1 = q1c.x, b2 = q1c.y;

    // first layer (revolution units): h_j = sin_rev(c . w[j,:] + b[j])
    float ha0, ha1, ha2, ha3, ha4;
    float hb0, hb1, hb2, hb3, hb4;
    {
        float za0 = fmaf(a2, fw[ 2], fmaf(a1, fw[ 1], fmaf(a0, fw[ 0], fw[15])));
        float zb0 = fmaf(b2, fw[ 2], fmaf(b1, fw[ 1], fmaf(b0, fw[ 0], fw[15])));
        float za1 = fmaf(a2, fw[ 5], fmaf(a1, fw[ 4], fmaf(a0, fw[ 3], fw[16])));
        float zb1 = fmaf(b2, fw[ 5], fmaf(b1, fw[ 4], fmaf(b0, fw[ 3], fw[16])));
        float za2 = fmaf(a2, fw[ 8], fmaf(a1, fw[ 7], fmaf(a0, fw[ 6], fw[17])));
        float zb2 = fmaf(b2, fw[ 8], fmaf(b1, fw[ 7], fmaf(b0, fw[ 6], fw[17])));
        float za3 = fmaf(a2, fw[11], fmaf(a1, fw[10], fmaf(a0, fw[ 9], fw[18])));
        float zb3 = fmaf(b2, fw[11], fmaf(b1, fw[10], fmaf(b0, fw[ 9], fw[18])));
        float za4 = fmaf(a2, fw[14], fmaf(a1, fw[13], fmaf(a0, fw[12], fw[19])));
        float zb4 = fmaf(b2, fw[14], fmaf(b1, fw[13], fmaf(b0, fw[12], fw[19])));
        ha0 = sinrev(za0); hb0 = sinrev(zb0);
        ha1 = sinrev(za1); hb1 = sinrev(zb1);
        ha2 = sinrev(za2); hb2 = sinrev(zb2);
        ha3 = sinrev(za3); hb3 = sinrev(zb3);
        ha4 = sinrev(za4); hb4 = sinrev(zb4);
    }

    // 256 hidden layers, weights broadcast from LDS (8x ds_read_b128/layer)
#pragma unroll 4
    for (int l = 0; l < SIREN_NLAYERS; ++l) {
        const float4* w4 = (const float4*)(slw + l * 32);
        float4 w0q = w4[0];   // w0  w1  w2  w3
        float4 w1q = w4[1];   // w4  w5  w6  w7
        float4 w2q = w4[2];   // w8  w9  w10 w11
        float4 w3q = w4[3];   // w12 w13 w14 w15
        float4 w4q = w4[4];   // w16 w17 w18 w19
        float4 w5q = w4[5];   // w20 w21 w22 w23
        float4 w6q = w4[6];   // w24 b0  b1  b2
        float4 w7q = w4[7];   // b3  b4  --  --

        float za0 = fmaf(ha4, w1q.x, fmaf(ha3, w0q.w, fmaf(ha2, w0q.z, fmaf(ha1, w0q.y, fmaf(ha0, w0q.x, w6q.y)))));
        float zb0 = fmaf(hb4, w1q.x, fmaf(hb3, w0q.w, fmaf(hb2, w0q.z, fmaf(hb1, w0q.y, fmaf(hb0, w0q.x, w6q.y)))));
        float za1 = fmaf(ha4, w2q.y, fmaf(ha3, w2q.x, fmaf(ha2, w1q.w, fmaf(ha1, w1q.z, fmaf(ha0, w1q.y, w6q.z)))));
        float zb1 = fmaf(hb4, w2q.y, fmaf(hb3, w2q.x, fmaf(hb2, w1q.w, fmaf(hb1, w1q.z, fmaf(hb0, w1q.y, w6q.z)))));
        float za2 = fmaf(ha4, w3q.z, fmaf(ha3, w3q.y, fmaf(ha2, w3q.x, fmaf(ha1, w2q.w, fmaf(ha0, w2q.z, w6q.w)))));
        float zb2 = fmaf(hb4, w3q.z, fmaf(hb3, w3q.y, fmaf(hb2, w3q.x, fmaf(hb1, w2q.w, fmaf(hb0, w2q.z, w6q.w)))));
        float za3 = fmaf(ha4, w4q.w, fmaf(ha3, w4q.z, fmaf(ha2, w4q.y, fmaf(ha1, w4q.x, fmaf(ha0, w3q.w, w7q.x)))));
        float zb3 = fmaf(hb4, w4q.w, fmaf(hb3, w4q.z, fmaf(hb2, w4q.y, fmaf(hb1, w4q.x, fmaf(hb0, w3q.w, w7q.x)))));
        float za4 = fmaf(ha4, w6q.x, fmaf(ha3, w5q.w, fmaf(ha2, w5q.z, fmaf(ha1, w5q.y, fmaf(ha0, w5q.x, w7q.y)))));
        float zb4 = fmaf(hb4, w6q.x, fmaf(hb3, w5q.w, fmaf(hb2, w5q.z, fmaf(hb1, w5q.y, fmaf(hb0, w5q.x, w7q.y)))));
        ha0 = sinrev(za0); hb0 = sinrev(zb0);
        ha1 = sinrev(za1); hb1 = sinrev(zb1);
        ha2 = sinrev(za2); hb2 = sinrev(zb2);
        ha3 = sinrev(za3); hb3 = sinrev(zb3);
        ha4 = sinrev(za4); hb4 = sinrev(zb4);
    }

    // final linear (plain units, no sine)
    float w0 = Wfin[0], w1 = Wfin[1], w2 = Wfin[2], w3 = Wfin[3], w4 = Wfin[4];
    float bb = bfin[0];
    float oa = fmaf(ha4, w4, fmaf(ha3, w3, fmaf(ha2, w2, fmaf(ha1, w1, fmaf(ha0, w0, bb)))));
    float ob = fmaf(hb4, w4, fmaf(hb3, w3, fmaf(hb2, w2, fmaf(hb1, w1, fmaf(hb0, w0, bb)))));

    out[2 * i + 0] = oa;
    out[2 * i + 1] = ob;

    // coords passthrough (second tuple element), 24B contiguous
    float* oc = out + N + 6 * i;
    *(float4*)(oc)     = q0c;
    *(float2*)(oc + 4) = q1c;
}

extern "C" void kernel_launch(void* const* d_in, const int* in_sizes, int n_in,
                              void* d_out, int out_size, void* d_ws, size_t ws_size,
                              hipStream_t stream) {
    const float* coords = (const float*)d_in[0];
    const float* Wf     = (const float*)d_in[1];
    const float* bf     = (const float*)d_in[2];
    const float* Wh     = (const float*)d_in[3];
    const float* bh     = (const float*)d_in[4];
    const float* Wfin   = (const float*)d_in[5];
    const float* bfin   = (const float*)d_in[6];

    int N = in_sizes[0] / 3;
    float* out = (float*)d_out;
    float* ws = (float*)d_ws;

    hipLaunchKernelGGL(siren_prep, dim3(32), dim3(256), 0, stream, Wf, bf, Wh, bh, ws);

    int M = N / 2;                       // pairs; N=524288 -> 262144 threads
    dim3 block(256);
    dim3 grid((M + 255) / 256);
    hipLaunchKernelGGL(siren_fwd7, grid, block, 0, stream,
                       coords, ws, ws + SIREN_NLAYERS * 32, Wfin, bfin, out, N);
}

// Round 8
// 162.484 us; speedup vs baseline: 1.0475x; 1.0475x over previous
//
#include <hip/hip_runtime.h>
#include <math.h>

// SIREN forward: coords [N,3] -> first(3->5,sin) -> 256 x hidden(5->5,sin) -> final(5->1)
// Output layout: d_out[0..N) = net output, d_out[N..4N) = coords passthrough.
//
// Round 8: P=4 + LDS weights + deg-9 poly sin.
//  - R2-R6: ~20% idle invariant to waves/SIMD -> all waves stall on the SAME
//    weight line per layer (shared s_load miss latency, ~150-200cyc/layer).
//  - R7 (P=2 + LDS) regressed because 16 waves/CU x 8 ds_read_b128 x ~12cyc
//    = 1536 cyc/CU-layer oversubscribed the single LDS pipe (vs 1080 VALU).
//  - At P=4: 8 waves/CU -> LDS demand 768 < VALU 1060 -> pipe fits. ds_reads
//    never miss; ~120cyc latency prefetched across the 530cyc layer body.
//  - Keep: deg-9 poly sin (8 full-rate VALU ops, err ~3e-5/sin), weights
//    prescaled by 30/(2pi) (rndne reduction exact), uniform clamp CF.

#define SIREN_HID 5
#define SIREN_NLAYERS 256
// 30 / (2*pi)
#define SIREN_REV 4.774648292756860f
#define PTS 4

// sin(2*pi*z) via degree-9 odd Chebyshev-truncated poly after exact range
// reduction. 8 full-rate VALU ops (rndne, sub, mul, 4x fma, mul).
__device__ __forceinline__ float sinrev(float z) {
    float k  = __builtin_rintf(z);         // v_rndne_f32
    float r  = z - k;                      // exact, r in [-0.5, 0.5]
    float r2 = r * r;
    float p  = fmaf(32.768f,       r2, -74.4734720f);
    p        = fmaf(p,             r2,  81.3648896f);
    p        = fmaf(p,             r2, -41.3310592f);
    p        = fmaf(p,             r2,   6.2830548f);
    return p * r;
}

// ---------------- prep: scale weights into revolution units ----------------
// d_ws layout (floats):
//   [0 .. 8192)        hidden layers: layer l at l*32: w[0..24], b[25..29], pad
//   [8192 .. 8207)     first layer W (5x3, row-major), scaled
//   [8207 .. 8212)     first layer b, scaled
__global__ __launch_bounds__(256)
void siren_prep(const float* __restrict__ Wf, const float* __restrict__ bf,
                const float* __restrict__ Wh, const float* __restrict__ bh,
                float* __restrict__ ws)
{
    int t = blockIdx.x * blockDim.x + threadIdx.x;
    const int total = SIREN_NLAYERS * 32;
    for (int idx = t; idx < total; idx += gridDim.x * blockDim.x) {
        int l = idx >> 5;
        int k = idx & 31;
        float v = 0.0f;
        if (k < 25)      v = Wh[l * 25 + k] * SIREN_REV;
        else if (k < 30) v = bh[l * 5 + (k - 25)] * SIREN_REV;
        ws[idx] = v;
    }
    if (t < 15) ws[total + t]      = Wf[t] * SIREN_REV;
    if (t < 5)  ws[total + 15 + t] = bf[t] * SIREN_REV;
}

// ---------------- main: 4 pts/thread, poly sin, LDS weights ----------------
__global__ __launch_bounds__(256)
void siren_fwd8(const float* __restrict__ coords,
                const float* __restrict__ lw,    // [256][32] scaled hidden w/b
                const float* __restrict__ fw,    // [20] scaled first w(15)+b(5)
                const float* __restrict__ Wfin,  // [1][5] (unscaled)
                const float* __restrict__ bfin,  // [1]
                float* __restrict__ out, int N)
{
    __shared__ float slw[SIREN_NLAYERS * 32];   // 32 KB

    // cooperative stage: 2048 float4s over 256 threads (coalesced)
    {
        const float4* g4 = (const float4*)lw;
        float4* s4 = (float4*)slw;
#pragma unroll
        for (int k = 0; k < 8; ++k)
            s4[threadIdx.x + k * 256] = g4[threadIdx.x + k * 256];
    }
    __syncthreads();

    int i = blockIdx.x * blockDim.x + threadIdx.x;
    const int M = N / PTS;                // groups of 4 points
    i = (i < M) ? i : (M - 1);            // uniform clamp, no divergent return

    // 4 adjacent points: 48B contiguous load as 3x float4
    const float4* cp4 = (const float4*)(coords + 3 * PTS * i);
    float4 q0 = cp4[0];   // a0 a1 a2 b0
    float4 q1 = cp4[1];   // b1 b2 c0 c1
    float4 q2 = cp4[2];   // c2 d0 d1 d2
    float c[PTS][3] = {
        { q0.x, q0.y, q0.z },
        { q0.w, q1.x, q1.y },
        { q1.z, q1.w, q2.x },
        { q2.y, q2.z, q2.w },
    };

    float h[PTS][SIREN_HID];

    // first layer (revolution units): h_j = sin_rev(c . w[j,:] + b[j])
#pragma unroll
    for (int p = 0; p < PTS; ++p) {
#pragma unroll
        for (int j = 0; j < SIREN_HID; ++j) {
            float z = fmaf(c[p][2], fw[3 * j + 2],
                      fmaf(c[p][1], fw[3 * j + 1],
                      fmaf(c[p][0], fw[3 * j + 0], fw[15 + j])));
            h[p][j] = sinrev(z);
        }
    }

    // 256 hidden layers, weights broadcast from LDS (8x ds_read_b128/layer)
#pragma unroll 2
    for (int l = 0; l < SIREN_NLAYERS; ++l) {
        const float4* w4 = (const float4*)(slw + l * 32);
        float4 w0q = w4[0];   // w0  w1  w2  w3
        float4 w1q = w4[1];   // w4  w5  w6  w7
        float4 w2q = w4[2];   // w8  w9  w10 w11
        float4 w3q = w4[3];   // w12 w13 w14 w15
        float4 w4q = w4[4];   // w16 w17 w18 w19
        float4 w5q = w4[5];   // w20 w21 w22 w23
        float4 w6q = w4[6];   // w24 b0  b1  b2
        float4 w7q = w4[7];   // b3  b4  --  --

        float z[PTS][SIREN_HID];
#pragma unroll
        for (int p = 0; p < PTS; ++p) {
            z[p][0] = fmaf(h[p][4], w1q.x, fmaf(h[p][3], w0q.w, fmaf(h[p][2], w0q.z, fmaf(h[p][1], w0q.y, fmaf(h[p][0], w0q.x, w6q.y)))));
            z[p][1] = fmaf(h[p][4], w2q.y, fmaf(h[p][3], w2q.x, fmaf(h[p][2], w1q.w, fmaf(h[p][1], w1q.z, fmaf(h[p][0], w1q.y, w6q.z)))));
            z[p][2] = fmaf(h[p][4], w3q.z, fmaf(h[p][3], w3q.y, fmaf(h[p][2], w3q.x, fmaf(h[p][1], w2q.w, fmaf(h[p][0], w2q.z, w6q.w)))));
            z[p][3] = fmaf(h[p][4], w4q.w, fmaf(h[p][3], w4q.z, fmaf(h[p][2], w4q.y, fmaf(h[p][1], w4q.x, fmaf(h[p][0], w3q.w, w7q.x)))));
            z[p][4] = fmaf(h[p][4], w6q.x, fmaf(h[p][3], w5q.w, fmaf(h[p][2], w5q.z, fmaf(h[p][1], w5q.y, fmaf(h[p][0], w5q.x, w7q.y)))));
        }
#pragma unroll
        for (int p = 0; p < PTS; ++p) {
#pragma unroll
            for (int j = 0; j < SIREN_HID; ++j)
                h[p][j] = sinrev(z[p][j]);
        }
    }

    // final linear (plain units, no sine)
    float w0 = Wfin[0], w1 = Wfin[1], w2 = Wfin[2], w3 = Wfin[3], w4 = Wfin[4];
    float bb = bfin[0];
    float o[PTS];
#pragma unroll
    for (int p = 0; p < PTS; ++p)
        o[p] = fmaf(h[p][4], w4, fmaf(h[p][3], w3, fmaf(h[p][2], w2, fmaf(h[p][1], w1, fmaf(h[p][0], w0, bb)))));

    // contiguous 16B store of the 4 outputs
    float4* op4 = (float4*)(out + PTS * i);
    *op4 = make_float4(o[0], o[1], o[2], o[3]);

    // coords passthrough (second tuple element), 48B contiguous
    float4* oc4 = (float4*)(out + N + 3 * PTS * i);
    oc4[0] = q0; oc4[1] = q1; oc4[2] = q2;
}

extern "C" void kernel_launch(void* const* d_in, const int* in_sizes, int n_in,
                              void* d_out, int out_size, void* d_ws, size_t ws_size,
                              hipStream_t stream) {
    const float* coords = (const float*)d_in[0];
    const float* Wf     = (const float*)d_in[1];
    const float* bf     = (const float*)d_in[2];
    const float* Wh     = (const float*)d_in[3];
    const float* bh     = (const float*)d_in[4];
    const float* Wfin   = (const float*)d_in[5];
    const float* bfin   = (const float*)d_in[6];

    int N = in_sizes[0] / 3;
    float* out = (float*)d_out;
    float* ws = (float*)d_ws;

    hipLaunchKernelGGL(siren_prep, dim3(32), dim3(256), 0, stream, Wf, bf, Wh, bh, ws);

    int M = N / PTS;                     // 4 points/thread; N=524288 -> 131072 threads
    dim3 block(256);
    dim3 grid((M + 255) / 256);
    hipLaunchKernelGGL(siren_fwd8, grid, block, 0, stream,
                       coords, ws, ws + SIREN_NLAYERS * 32, Wfin, bfin, out, N);
}

// Round 10
// 154.295 us; speedup vs baseline: 1.1031x; 1.0531x over previous
//
#include <hip/hip_runtime.h>
#include <math.h>

// SIREN forward: coords [N,3] -> first(3->5,sin) -> 256 x hidden(5->5,sin) -> final(5->1)
// Output layout: d_out[0..N) = net output, d_out[N..4N) = coords passthrough.
//
// Round 10 (= round 9 with the macro token-paste bug fixed via register
// arrays + inline functions; constant indices only, no scratch risk):
//  - Manual double-buffered weight prefetch. R2-R8: busy cyc/pt-layer at the
//    issue floor everywhere; idle pinned at 20-27%, invariant to TLP/ILP ->
//    every wave eats the same per-layer weight-load latency (~120-200cyc),
//    compiler never hoists loads a layer ahead (VGPR=48 at default bounds).
//    Fix: __launch_bounds__(256,2) for VGPR headroom + explicit unroll-2
//    double buffer in float4 wa[8]/wb[8], prefetch issued one full layer
//    (~530 compute cycles) before first use.
//  - Keep: P=4, deg-9 poly sin (8 full-rate VALU ops, err ~3e-5/sin), weights
//    prescaled by 30/(2pi) (rndne reduction exact), uniform clamp CF,
//    LDS-staged weights (padded +1 layer so the last prefetch is in-bounds).

#define SIREN_HID 5
#define SIREN_NLAYERS 256
// 30 / (2*pi)
#define SIREN_REV 4.774648292756860f
#define PTS 4

// sin(2*pi*z) via degree-9 odd Chebyshev-truncated poly after exact range
// reduction. 8 full-rate VALU ops (rndne, sub, mul, 4x fma, mul).
__device__ __forceinline__ float sinrev(float z) {
    float k  = __builtin_rintf(z);         // v_rndne_f32
    float r  = z - k;                      // exact, r in [-0.5, 0.5]
    float r2 = r * r;
    float p  = fmaf(32.768f,       r2, -74.4734720f);
    p        = fmaf(p,             r2,  81.3648896f);
    p        = fmaf(p,             r2, -41.3310592f);
    p        = fmaf(p,             r2,   6.2830548f);
    return p * r;
}

// ---------------- prep: scale weights into revolution units ----------------
// d_ws layout (floats):
//   [0 .. 8192)        hidden layers: layer l at l*32: w[0..24], b[25..29], pad
//   [8192 .. 8207)     first layer W (5x3, row-major), scaled
//   [8207 .. 8212)     first layer b, scaled
__global__ __launch_bounds__(256)
void siren_prep(const float* __restrict__ Wf, const float* __restrict__ bf,
                const float* __restrict__ Wh, const float* __restrict__ bh,
                float* __restrict__ ws)
{
    int t = blockIdx.x * blockDim.x + threadIdx.x;
    const int total = SIREN_NLAYERS * 32;
    for (int idx = t; idx < total; idx += gridDim.x * blockDim.x) {
        int l = idx >> 5;
        int k = idx & 31;
        float v = 0.0f;
        if (k < 25)      v = Wh[l * 25 + k] * SIREN_REV;
        else if (k < 30) v = bh[l * 5 + (k - 25)] * SIREN_REV;
        ws[idx] = v;
    }
    if (t < 15) ws[total + t]      = Wf[t] * SIREN_REV;
    if (t < 5)  ws[total + 15 + t] = bf[t] * SIREN_REV;
}

// load layer's 32 floats into 8 float4 regs (8x ds_read_b128)
__device__ __forceinline__ void prefetch_layer(float4 w[8], const float* slw, int l) {
    const float4* p4 = (const float4*)(slw + l * 32);
#pragma unroll
    for (int k = 0; k < 8; ++k) w[k] = p4[k];
}

// one hidden layer for all PTS points from weight regs
// layout: w0..w24 in w[0].x..w[6].x, biases b0..b4 in w[6].y..w[7].y
__device__ __forceinline__ void layer_step(float h[PTS][SIREN_HID], const float4 w[8]) {
    float z[PTS][SIREN_HID];
#pragma unroll
    for (int p = 0; p < PTS; ++p) {
        z[p][0] = fmaf(h[p][4], w[1].x, fmaf(h[p][3], w[0].w, fmaf(h[p][2], w[0].z, fmaf(h[p][1], w[0].y, fmaf(h[p][0], w[0].x, w[6].y)))));
        z[p][1] = fmaf(h[p][4], w[2].y, fmaf(h[p][3], w[2].x, fmaf(h[p][2], w[1].w, fmaf(h[p][1], w[1].z, fmaf(h[p][0], w[1].y, w[6].z)))));
        z[p][2] = fmaf(h[p][4], w[3].z, fmaf(h[p][3], w[3].y, fmaf(h[p][2], w[3].x, fmaf(h[p][1], w[2].w, fmaf(h[p][0], w[2].z, w[6].w)))));
        z[p][3] = fmaf(h[p][4], w[4].w, fmaf(h[p][3], w[4].z, fmaf(h[p][2], w[4].y, fmaf(h[p][1], w[4].x, fmaf(h[p][0], w[3].w, w[7].x)))));
        z[p][4] = fmaf(h[p][4], w[6].x, fmaf(h[p][3], w[5].w, fmaf(h[p][2], w[5].z, fmaf(h[p][1], w[5].y, fmaf(h[p][0], w[5].x, w[7].y)))));
    }
#pragma unroll
    for (int p = 0; p < PTS; ++p) {
#pragma unroll
        for (int j = 0; j < SIREN_HID; ++j)
            h[p][j] = sinrev(z[p][j]);
    }
}

// ---------------- main: 4 pts/thread, poly sin, LDS + reg double-buffer ------
__global__ __launch_bounds__(256, 2)
void siren_fwd10(const float* __restrict__ coords,
                 const float* __restrict__ lw,    // [256][32] scaled hidden w/b
                 const float* __restrict__ fw,    // [20] scaled first w(15)+b(5)
                 const float* __restrict__ Wfin,  // [1][5] (unscaled)
                 const float* __restrict__ bfin,  // [1]
                 float* __restrict__ out, int N)
{
    __shared__ float slw[(SIREN_NLAYERS + 1) * 32];   // +1 layer pad for last prefetch

    // cooperative stage: 2048 float4s over 256 threads (coalesced); zero the pad
    {
        const float4* g4 = (const float4*)lw;
        float4* s4 = (float4*)slw;
#pragma unroll
        for (int k = 0; k < 8; ++k)
            s4[threadIdx.x + k * 256] = g4[threadIdx.x + k * 256];
        if (threadIdx.x < 8)
            s4[2048 + threadIdx.x] = make_float4(0.f, 0.f, 0.f, 0.f);
    }
    __syncthreads();

    int i = blockIdx.x * blockDim.x + threadIdx.x;
    const int M = N / PTS;                // groups of 4 points
    i = (i < M) ? i : (M - 1);            // uniform clamp, no divergent return

    // 4 adjacent points: 48B contiguous load as 3x float4
    const float4* cp4 = (const float4*)(coords + 3 * PTS * i);
    float4 q0 = cp4[0];   // a0 a1 a2 b0
    float4 q1 = cp4[1];   // b1 b2 c0 c1
    float4 q2 = cp4[2];   // c2 d0 d1 d2
    float c[PTS][3] = {
        { q0.x, q0.y, q0.z },
        { q0.w, q1.x, q1.y },
        { q1.z, q1.w, q2.x },
        { q2.y, q2.z, q2.w },
    };

    float h[PTS][SIREN_HID];

    // first layer (revolution units): h_j = sin_rev(c . w[j,:] + b[j])
#pragma unroll
    for (int p = 0; p < PTS; ++p) {
#pragma unroll
        for (int j = 0; j < SIREN_HID; ++j) {
            float z = fmaf(c[p][2], fw[3 * j + 2],
                      fmaf(c[p][1], fw[3 * j + 1],
                      fmaf(c[p][0], fw[3 * j + 0], fw[15 + j])));
            h[p][j] = sinrev(z);
        }
    }

    // 256 hidden layers: double-buffered weight regs, prefetch one layer ahead
    float4 wa[8], wb[8];
    prefetch_layer(wa, slw, 0);
    for (int l = 0; l < SIREN_NLAYERS; l += 2) {
        prefetch_layer(wb, slw, l + 1);   // in flight during layer_step(wa)
        layer_step(h, wa);
        prefetch_layer(wa, slw, l + 2);   // l=254 -> padded zero layer, unused
        layer_step(h, wb);
    }

    // final linear (plain units, no sine)
    float w0 = Wfin[0], w1 = Wfin[1], w2 = Wfin[2], w3 = Wfin[3], w4 = Wfin[4];
    float bb = bfin[0];
    float o[PTS];
#pragma unroll
    for (int p = 0; p < PTS; ++p)
        o[p] = fmaf(h[p][4], w4, fmaf(h[p][3], w3, fmaf(h[p][2], w2, fmaf(h[p][1], w1, fmaf(h[p][0], w0, bb)))));

    // contiguous 16B store of the 4 outputs
    float4* op4 = (float4*)(out + PTS * i);
    *op4 = make_float4(o[0], o[1], o[2], o[3]);

    // coords passthrough (second tuple element), 48B contiguous
    float4* oc4 = (float4*)(out + N + 3 * PTS * i);
    oc4[0] = q0; oc4[1] = q1; oc4[2] = q2;
}

extern "C" void kernel_launch(void* const* d_in, const int* in_sizes, int n_in,
                              void* d_out, int out_size, void* d_ws, size_t ws_size,
                              hipStream_t stream) {
    const float* coords = (const float*)d_in[0];
    const float* Wf     = (const float*)d_in[1];
    const float* bf     = (const float*)d_in[2];
    const float* Wh     = (const float*)d_in[3];
    const float* bh     = (const float*)d_in[4];
    const float* Wfin   = (const float*)d_in[5];
    const float* bfin   = (const float*)d_in[6];

    int N = in_sizes[0] / 3;
    float* out = (float*)d_out;
    float* ws = (float*)d_ws;

    hipLaunchKernelGGL(siren_prep, dim3(32), dim3(256), 0, stream, Wf, bf, Wh, bh, ws);

    int M = N / PTS;                     // 4 points/thread; N=524288 -> 131072 threads
    dim3 block(256);
    dim3 grid((M + 255) / 256);
    hipLaunchKernelGGL(siren_fwd10, grid, block, 0, stream,
                       coords, ws, ws + SIREN_NLAYERS * 32, Wfin, bfin, out, N);
}